// Round 9
// baseline (460.932 us; speedup 1.0000x reference)
//
#include <hip/hip_runtime.h>
#include <math.h>

typedef _Float16 f16x8 __attribute__((ext_vector_type(8)));
typedef _Float16 f16x4 __attribute__((ext_vector_type(4)));
typedef float f32x4 __attribute__((ext_vector_type(4)));

#define TLEN 512
#define BT 16
#define MFMA(a,b,c) __builtin_amdgcn_mfma_f32_16x16x32_f16(a,b,c,0,0,0)
#define LOG2E 1.44269504f

__device__ __forceinline__ float sigmoid2_f(float x) {
    return __builtin_amdgcn_rcpf(1.f + __builtin_amdgcn_exp2f(-LOG2E * x));
}
__device__ __forceinline__ float tanh2_f(float x) {
    float t = __builtin_amdgcn_rcpf(1.f + __builtin_amdgcn_exp2f(2.f * LOG2E * x));
    return fmaf(-2.f, t, 1.f);
}

// R9: R8 structure with gi SOFTWARE-PIPELINED one step ahead:
//   step t consumes gi(t) computed at step t-1 (as MFMA C-seed, ready in regs
//   before the barrier), and computes gi(t+1) from x(t+1) (loaded at t-1)
//   under the MFMA shadow. x(t+2) prefetched at t -> full step of load slack.
// Critical path: barrier -> 4x ds_read_b128 -> 18 MFMA (3 RR chains of 6)
//   -> gates -> pack/ds_write. All gi/dec/prefetch VALU hides under MFMA.
// Layout (verified R6): A = w_hh (VGPR, fp16 hi/lo), B = state (LDS),
// C[m=hidden(quad*4+r)][n=batch(lane&15)]. Biases + gi exact fp32 via C-seed.
__global__ __launch_bounds__(256, 1) void grut1_kernel(
    const float* __restrict__ X, const float* __restrict__ dtp,
    const float* __restrict__ w_ih, const float* __restrict__ w_hh,
    const float* __restrict__ b_ih, const float* __restrict__ b_hh,
    const float* __restrict__ w_dt, const float* __restrict__ b_dt,
    const float* __restrict__ w_out, const float* __restrict__ b_out,
    float* __restrict__ out)
{
    __shared__ __align__(16) _Float16 Bs[4096];    // [phase2][plane2][kt2][512]
    __shared__ __align__(16) float PPc[512];       // [wave4][b16][t8]

    const int tid = threadIdx.x;
    const int w = tid >> 6;
    const int l = tid & 63;
    const int n16 = l & 15;
    const int quad = l >> 4;
    const int b0g = blockIdx.x * BT;
    const int hq0 = w * 16 + quad * 4;

    // B-state publish offset (halfwords), verified R6
    const int bsoff = (w >> 1) * 512
                    + (((2 * (w & 1) + (quad >> 1)) * 16) + n16) * 8
                    + (quad & 1) * 4;

    float wdt4[4], bdt4[4], wout4[4], biasNh[4], biasR[4], biasZ[4], biasN[4];
#pragma unroll
    for (int r = 0; r < 4; ++r) {
        int j = hq0 + r;
        wdt4[r] = w_dt[j];
        bdt4[r] = b_dt[j];
        wout4[r] = w_out[j];
        biasR[r] = b_ih[j] + b_hh[j];
        biasZ[r] = b_ih[64 + j] + b_hh[64 + j];
        biasN[r] = b_ih[128 + j];
        biasNh[r] = b_hh[128 + j];
    }
    const float bout = b_out[0];

    // w_ih rows for lane's 4 hidden x 3 gates (exact fp32, VGPR-resident)
    float wih[3][4][5];
#pragma unroll
    for (int g = 0; g < 3; ++g)
#pragma unroll
        for (int r = 0; r < 4; ++r)
#pragma unroll
            for (int f = 0; f < 5; ++f)
                wih[g][r][f] = w_ih[(g * 64 + hq0 + r) * 5 + f];

    // A-frags (w_hh), fp16 hi/lo, VGPR-resident. A[m=l&15][k=quad*8+j].
    f16x8 Ah[3][2], Al[3][2];
#pragma unroll
    for (int g = 0; g < 3; ++g) {
        const int row = g * 64 + w * 16 + n16;
#pragma unroll
        for (int kt = 0; kt < 2; ++kt) {
            const float* src = w_hh + row * 64 + kt * 32 + quad * 8;
            f16x8 hi, lo;
#pragma unroll
            for (int i = 0; i < 8; ++i) {
                float v = src[i];
                _Float16 h = (_Float16)v;
                hi[i] = h;
                lo[i] = (_Float16)(v - (float)h);
            }
            Ah[g][kt] = hi;
            Al[g][kt] = lo;
        }
    }

    const float* xrow = X + (size_t)(b0g + n16) * TLEN * 5;
    const float* dtb = dtp + (size_t)(b0g + n16) * TLEN;

    // gi(0) from x(0); xc = x(1) (for gi(1) computed during step 0)
    float xc[5], xn[5];
    f32x4 giR_c, giZ_c, giN_c, giR_n, giZ_n, giN_n;
    {
        float x0[5];
#pragma unroll
        for (int f = 0; f < 5; ++f) x0[f] = xrow[f];
#pragma unroll
        for (int r = 0; r < 4; ++r) {
            giR_c[r] = fmaf(wih[0][r][4], x0[4], fmaf(wih[0][r][3], x0[3],
                       fmaf(wih[0][r][2], x0[2], fmaf(wih[0][r][1], x0[1],
                       fmaf(wih[0][r][0], x0[0], biasR[r])))));
            giZ_c[r] = fmaf(wih[1][r][4], x0[4], fmaf(wih[1][r][3], x0[3],
                       fmaf(wih[1][r][2], x0[2], fmaf(wih[1][r][1], x0[1],
                       fmaf(wih[1][r][0], x0[0], biasZ[r])))));
            giN_c[r] = fmaf(wih[2][r][4], x0[4], fmaf(wih[2][r][3], x0[3],
                       fmaf(wih[2][r][2], x0[2], fmaf(wih[2][r][1], x0[1],
                       fmaf(wih[2][r][0], x0[0], biasN[r])))));
        }
#pragma unroll
        for (int f = 0; f < 5; ++f) xc[f] = xrow[5 + f];
    }

    // chunk-0 dt + dec(0)
    float4 dtc0 = *(const float4*)(dtb);
    float4 dtc1 = *(const float4*)(dtb + 4);
    float4 dtn0, dtn1;
    float dcur[4];
#pragma unroll
    for (int r = 0; r < 4; ++r)
        dcur[r] = __builtin_amdgcn_exp2f(-LOG2E * fmaxf(fmaf(dtc0.x, wdt4[r], bdt4[r]), 0.f));

    f32x4 hreg = {0.f, 0.f, 0.f, 0.f};
    const f32x4 zero4 = {0.f, 0.f, 0.f, 0.f};
    float pbuf[8];

#pragma unroll 1
    for (int tb = 0; tb < TLEN; tb += 8) {
#pragma unroll
        for (int sub = 0; sub < 8; ++sub) {
            const int t = tb + sub;
            const int pB = (sub & 1) * 2048;

            // ---- pre-barrier: h_tilde pack + state publish (2x ds_write_b64) ----
            f32x4 htl;
            f16x4 vh, vl;
#pragma unroll
            for (int r = 0; r < 4; ++r) {
                float v = dcur[r] * hreg[r];
                htl[r] = v;
                _Float16 h = (_Float16)v;
                vh[r] = h;
                vl[r] = (_Float16)(v - (float)h);
            }
            *(f16x4*)&Bs[pB + bsoff] = vh;
            *(f16x4*)&Bs[pB + 1024 + bsoff] = vl;

            __syncthreads();

            // ---- post-barrier: B-frag reads (4x ds_read_b128) ----
            f16x8 Bh0 = *(const f16x8*)&Bs[pB + l * 8];
            f16x8 Bh1 = *(const f16x8*)&Bs[pB + 512 + l * 8];
            f16x8 Bl0 = *(const f16x8*)&Bs[pB + 1024 + l * 8];
            f16x8 Bl1 = *(const f16x8*)&Bs[pB + 1536 + l * 8];

            // ---- 18 MFMA: 3 round-robin chains of 6, gi(t) as ready C-seed ----
            f32x4 aR = giR_c, aZ = giZ_c, aNh = zero4;
            aR  = MFMA(Ah[0][0], Bh0, aR);
            aZ  = MFMA(Ah[1][0], Bh0, aZ);
            aNh = MFMA(Ah[2][0], Bh0, aNh);
            aR  = MFMA(Al[0][0], Bh0, aR);
            aZ  = MFMA(Al[1][0], Bh0, aZ);
            aNh = MFMA(Al[2][0], Bh0, aNh);
            aR  = MFMA(Ah[0][0], Bl0, aR);
            aZ  = MFMA(Ah[1][0], Bl0, aZ);
            aNh = MFMA(Ah[2][0], Bl0, aNh);
            aR  = MFMA(Ah[0][1], Bh1, aR);
            aZ  = MFMA(Ah[1][1], Bh1, aZ);
            aNh = MFMA(Ah[2][1], Bh1, aNh);
            aR  = MFMA(Al[0][1], Bh1, aR);
            aZ  = MFMA(Al[1][1], Bh1, aZ);
            aNh = MFMA(Al[2][1], Bh1, aNh);
            aR  = MFMA(Ah[0][1], Bl1, aR);
            aZ  = MFMA(Ah[1][1], Bl1, aZ);
            aNh = MFMA(Ah[2][1], Bl1, aNh);

            // ---- under MFMA shadow: prefetches + gi(t+1) + dec(t+1) ----
            if (sub == 0 && tb > 0 && tid < 128) {
                int b = tid >> 3, t8 = tid & 7;
                int base = b * 8 + t8;
                float s = PPc[base] + PPc[128 + base] + PPc[256 + base] + PPc[384 + base];
                out[(size_t)(b0g + b) * TLEN + (tb - 8) + t8] = s + bout;
            }
            if (t + 2 < TLEN) {
#pragma unroll
                for (int f = 0; f < 5; ++f) xn[f] = xrow[(t + 2) * 5 + f];
            }
            if (sub == 2 && tb + 8 < TLEN) {
                dtn0 = *(const float4*)(dtb + tb + 8);
                dtn1 = *(const float4*)(dtb + tb + 12);
            }
            // gi(t+1) from xc = x(t+1), loaded at step t-1 (full-step slack)
#pragma unroll
            for (int r = 0; r < 4; ++r) {
                giR_n[r] = fmaf(wih[0][r][4], xc[4], fmaf(wih[0][r][3], xc[3],
                           fmaf(wih[0][r][2], xc[2], fmaf(wih[0][r][1], xc[1],
                           fmaf(wih[0][r][0], xc[0], biasR[r])))));
                giZ_n[r] = fmaf(wih[1][r][4], xc[4], fmaf(wih[1][r][3], xc[3],
                           fmaf(wih[1][r][2], xc[2], fmaf(wih[1][r][1], xc[1],
                           fmaf(wih[1][r][0], xc[0], biasZ[r])))));
                giN_n[r] = fmaf(wih[2][r][4], xc[4], fmaf(wih[2][r][3], xc[3],
                           fmaf(wih[2][r][2], xc[2], fmaf(wih[2][r][1], xc[1],
                           fmaf(wih[2][r][0], xc[0], biasN[r])))));
            }
            if (tb + 8 < TLEN || sub < 7) {
                float dnext = (sub == 0) ? dtc0.y : (sub == 1) ? dtc0.z : (sub == 2) ? dtc0.w
                            : (sub == 3) ? dtc1.x : (sub == 4) ? dtc1.y : (sub == 5) ? dtc1.z
                            : (sub == 6) ? dtc1.w : dtn0.x;
#pragma unroll
                for (int r = 0; r < 4; ++r)
                    dcur[r] = __builtin_amdgcn_exp2f(-LOG2E * fmaxf(fmaf(dnext, wdt4[r], bdt4[r]), 0.f));
            }

            // ---- gates + h update + pred ----
            float p = 0.f;
#pragma unroll
            for (int r = 0; r < 4; ++r) {
                float rr = sigmoid2_f(aR[r]);
                float zz = sigmoid2_f(aZ[r]);
                float nn = tanh2_f(giN_c[r] + rr * (aNh[r] + biasNh[r]));
                float hv = fmaf(zz, htl[r] - nn, nn);
                hreg[r] = hv;
                p = fmaf(wout4[r], hv, p);
            }
            p += __shfl_xor(p, 16, 64);
            p += __shfl_xor(p, 32, 64);
            pbuf[sub] = p;

            // rotate pipeline regs
            giR_c = giR_n; giZ_c = giZ_n; giN_c = giN_n;
#pragma unroll
            for (int f = 0; f < 5; ++f) xc[f] = xn[f];

            if (sub == 7) {
                if (l < 16) {
                    f32x4 v0 = {pbuf[0], pbuf[1], pbuf[2], pbuf[3]};
                    f32x4 v1 = {pbuf[4], pbuf[5], pbuf[6], pbuf[7]};
                    *(f32x4*)&PPc[w * 128 + n16 * 8] = v0;
                    *(f32x4*)&PPc[w * 128 + n16 * 8 + 4] = v1;
                }
                dtc0 = dtn0;
                dtc1 = dtn1;
            }
        }
    }

    // final chunk combine
    __syncthreads();
    if (tid < 128) {
        int b = tid >> 3, t8 = tid & 7;
        int base = b * 8 + t8;
        float s = PPc[base] + PPc[128 + base] + PPc[256 + base] + PPc[384 + base];
        out[(size_t)(b0g + b) * TLEN + (TLEN - 8) + t8] = s + bout;
    }
}

extern "C" void kernel_launch(void* const* d_in, const int* in_sizes, int n_in,
                              void* d_out, int out_size, void* d_ws, size_t ws_size,
                              hipStream_t stream) {
    const float* X    = (const float*)d_in[0];
    const float* dt   = (const float*)d_in[1];
    const float* w_ih = (const float*)d_in[2];
    const float* w_hh = (const float*)d_in[3];
    const float* b_ih = (const float*)d_in[4];
    const float* b_hh = (const float*)d_in[5];
    const float* w_dt = (const float*)d_in[6];
    const float* b_dt = (const float*)d_in[7];
    const float* w_out = (const float*)d_in[8];
    const float* b_out = (const float*)d_in[9];
    float* out = (float*)d_out;

    grut1_kernel<<<dim3(4096 / BT), dim3(256), 0, stream>>>(
        X, dt, w_ih, w_hh, b_ih, b_hh, w_dt, b_dt, w_out, b_out, out);
}

// Round 10
// 398.594 us; speedup vs baseline: 1.1564x; 1.1564x over previous
//
#include <hip/hip_runtime.h>
#include <math.h>

typedef _Float16 f16x8 __attribute__((ext_vector_type(8)));
typedef _Float16 f16x4 __attribute__((ext_vector_type(4)));
typedef float f32x4 __attribute__((ext_vector_type(4)));

#define TLEN 512
#define BT 16
#define MFMA(a,b,c) __builtin_amdgcn_mfma_f32_16x16x32_f16(a,b,c,0,0,0)
#define LOG2E 1.44269504f

// Workgroup barrier WITHOUT the vmcnt(0)/expcnt(0) drain __syncthreads emits.
// Safe here: only LDS data crosses the barrier (lgkmcnt(0) orders ds_writes);
// global loads are wave-private (compiler inserts vmcnt waits at use);
// out-stores are never re-read in-kernel.
__device__ __forceinline__ void bar_lds() {
    asm volatile("s_waitcnt lgkmcnt(0)\n\ts_barrier" ::: "memory");
}

__device__ __forceinline__ float sigmoid2_f(float x) {
    return __builtin_amdgcn_rcpf(1.f + __builtin_amdgcn_exp2f(-LOG2E * x));
}
__device__ __forceinline__ float tanh2_f(float x) {
    float t = __builtin_amdgcn_rcpf(1.f + __builtin_amdgcn_exp2f(2.f * LOG2E * x));
    return fmaf(-2.f, t, 1.f);
}

// R10 = R6 (best, 399us) with ONE change: in-loop __syncthreads -> bar_lds()
// (no vmcnt drain). R6 structure: 256 blocks x 256 thr, BT=16, 1 block/CU.
// A = weights (VGPR, fp16 hi/lo), B = state/x (LDS).
// C[m=hidden(quad*4+r)][n=batch(lane&15)]. Biases exact fp32 via C-seed.
// 27 MFMA/step: 3 gates x (2 state ktiles + 1 x ktile) x 3-term hi/lo split.
__global__ __launch_bounds__(256, 1) void grut1_kernel(
    const float* __restrict__ X, const float* __restrict__ dtp,
    const float* __restrict__ w_ih, const float* __restrict__ w_hh,
    const float* __restrict__ b_ih, const float* __restrict__ b_hh,
    const float* __restrict__ w_dt, const float* __restrict__ b_dt,
    const float* __restrict__ w_out, const float* __restrict__ b_out,
    float* __restrict__ out)
{
    __shared__ __align__(16) _Float16 Bs[4096];    // [phase2][plane2][kt2][512]
    __shared__ __align__(16) _Float16 Bx[16384];   // [par2][t8][plane2][512]
    __shared__ __align__(16) float PPc[512];       // [wave4][b16][t8]

    const int tid = threadIdx.x;
    const int w = tid >> 6;
    const int l = tid & 63;
    const int n16 = l & 15;
    const int quad = l >> 4;
    const int b0g = blockIdx.x * BT;
    const int hq0 = w * 16 + quad * 4;

    // B-state publish offset (halfwords): k_local = 16(w&1)+4q+r, contiguous r
    const int bsoff = (w >> 1) * 512
                    + (((2 * (w & 1) + (quad >> 1)) * 16) + n16) * 8
                    + (quad & 1) * 4;

    float wdt4[4], bdt4[4], wout4[4], biasNh[4];
    f32x4 seedR, seedZ, seedNi;
    const f32x4 zero4 = {0.f, 0.f, 0.f, 0.f};
#pragma unroll
    for (int r = 0; r < 4; ++r) {
        int j = hq0 + r;
        wdt4[r] = w_dt[j];
        bdt4[r] = b_dt[j];
        wout4[r] = w_out[j];
        seedR[r] = b_ih[j] + b_hh[j];
        seedZ[r] = b_ih[64 + j] + b_hh[64 + j];
        seedNi[r] = b_ih[128 + j];
        biasNh[r] = b_hh[128 + j];
    }
    const float bout = b_out[0];

    // A-frags (weights), fp16 hi/lo, VGPR-resident. A[m=l&15][k=quad*8+j].
    f16x8 Ah[3][2], Al[3][2], Axh[3], Axl[3];
#pragma unroll
    for (int g = 0; g < 3; ++g) {
        const int row = g * 64 + w * 16 + n16;
#pragma unroll
        for (int kt = 0; kt < 2; ++kt) {
            const float* src = w_hh + row * 64 + kt * 32 + quad * 8;
            f16x8 hi, lo;
#pragma unroll
            for (int i = 0; i < 8; ++i) {
                float v = src[i];
                _Float16 h = (_Float16)v;
                hi[i] = h;
                lo[i] = (_Float16)(v - (float)h);
            }
            Ah[g][kt] = hi;
            Al[g][kt] = lo;
        }
        f16x8 hi, lo;
#pragma unroll
        for (int i = 0; i < 8; ++i) {
            float v = (quad == 0 && i < 5) ? w_ih[row * 5 + i] : 0.f;
            _Float16 h = (_Float16)v;
            hi[i] = h;
            lo[i] = (_Float16)(v - (float)h);
        }
        Axh[g] = hi;
        Axl[g] = lo;
    }

    // x staging map: v in [0,640) -> b = v/40, rem = v%40, tt = rem/5, f = rem%5
    int xg[3], xw[3], xvalid[3];
#pragma unroll
    for (int i = 0; i < 3; ++i) {
        int v = tid + i * 256;
        xvalid[i] = (v < 640);
        int vv = xvalid[i] ? v : 0;
        int b = vv / 40;
        int rem = vv - b * 40;
        int tt = rem / 5;
        int f = rem - tt * 5;
        xg[i] = (b0g + b) * (TLEN * 5) + rem;
        xw[i] = tt * 1024 + b * 8 + f;
    }

    // zero Bx (unused K slots must be 0.0f16)
    {
        float4 z4 = make_float4(0.f, 0.f, 0.f, 0.f);
        float4* p4 = (float4*)Bx;
#pragma unroll
        for (int i = 0; i < 8; ++i) p4[tid + i * 256] = z4;
    }
    __syncthreads();
    // publish chunk-0 x
#pragma unroll
    for (int i = 0; i < 3; ++i) if (xvalid[i]) {
        float v = X[xg[i]];
        _Float16 h = (_Float16)v;
        Bx[xw[i]] = h;
        Bx[512 + xw[i]] = (_Float16)(v - (float)h);
    }

    // chunk-0 dt (lane's batch) + dec for t=0
    const float* dtb = dtp + (size_t)(b0g + n16) * TLEN;
    float4 dtc0 = *(const float4*)(dtb);
    float4 dtc1 = *(const float4*)(dtb + 4);
    float4 dtn0, dtn1;
    float dcur[4];
#pragma unroll
    for (int r = 0; r < 4; ++r)
        dcur[r] = __builtin_amdgcn_exp2f(-LOG2E * fmaxf(fmaf(dtc0.x, wdt4[r], bdt4[r]), 0.f));

    f32x4 hreg = {0.f, 0.f, 0.f, 0.f};
    float pbuf[8];
    float xst[3];

#pragma unroll 1
    for (int tb = 0; tb < TLEN; tb += 8) {
        const int par = (tb >> 3) & 1;
        const int npar = par ^ 1;
#pragma unroll
        for (int sub = 0; sub < 8; ++sub) {
            const int pB = (sub & 1) * 2048;

            // ---- pre-barrier: h_tilde pack + state publish (2x ds_write_b64) ----
            f32x4 htl;
            f16x4 vh, vl;
#pragma unroll
            for (int r = 0; r < 4; ++r) {
                float v = dcur[r] * hreg[r];
                htl[r] = v;
                _Float16 h = (_Float16)v;
                vh[r] = h;
                vl[r] = (_Float16)(v - (float)h);
            }
            *(f16x4*)&Bs[pB + bsoff] = vh;
            *(f16x4*)&Bs[pB + 1024 + bsoff] = vl;
            if (sub == 7 && tb + 8 < TLEN) {
                // publish next chunk's x-frags
#pragma unroll
                for (int i = 0; i < 3; ++i) if (xvalid[i]) {
                    float v = xst[i];
                    _Float16 h = (_Float16)v;
                    Bx[npar * 8192 + xw[i]] = h;
                    Bx[npar * 8192 + 512 + xw[i]] = (_Float16)(v - (float)h);
                }
            }

            bar_lds();   // lgkmcnt(0) + s_barrier only -- NO vmcnt drain

            // ---- post-barrier: B-frag reads ----
            f16x8 Bh0 = *(const f16x8*)&Bs[pB + l * 8];
            f16x8 Bh1 = *(const f16x8*)&Bs[pB + 512 + l * 8];
            f16x8 Bl0 = *(const f16x8*)&Bs[pB + 1024 + l * 8];
            f16x8 Bl1 = *(const f16x8*)&Bs[pB + 1536 + l * 8];
            f16x8 Bxh = *(const f16x8*)&Bx[par * 8192 + sub * 1024 + l * 8];
            f16x8 Bxl = *(const f16x8*)&Bx[par * 8192 + sub * 1024 + 512 + l * 8];

            // prev-chunk output combine (piggybacks on this barrier)
            if (sub == 0 && tb > 0 && tid < 128) {
                int b = tid >> 3, t8 = tid & 7;
                int base = b * 8 + t8;
                float s = PPc[base] + PPc[128 + base] + PPc[256 + base] + PPc[384 + base];
                out[(size_t)(b0g + b) * TLEN + (tb - 8) + t8] = s + bout;
            }
            // next-chunk prefetches (latency covered until consumed; no drains)
            if (sub == 1 && tb + 8 < TLEN) {
#pragma unroll
                for (int i = 0; i < 3; ++i) if (xvalid[i]) xst[i] = X[xg[i] + (tb + 8) * 5];
            }
            if (sub == 2 && tb + 8 < TLEN) {
                dtn0 = *(const float4*)(dtb + tb + 8);
                dtn1 = *(const float4*)(dtb + tb + 12);
            }

            // ---- 27 MFMA, 4 chains (R:9, Z:9, Nh:6, Ni:3), bias-seeded ----
            f32x4 aR = seedR, aZ = seedZ, aNi = seedNi, aNh = zero4;
            aR  = MFMA(Ah[0][0], Bh0, aR);
            aZ  = MFMA(Ah[1][0], Bh0, aZ);
            aNh = MFMA(Ah[2][0], Bh0, aNh);
            aNi = MFMA(Axh[2], Bxh, aNi);
            aR  = MFMA(Al[0][0], Bh0, aR);
            aZ  = MFMA(Al[1][0], Bh0, aZ);
            aNh = MFMA(Al[2][0], Bh0, aNh);
            aNi = MFMA(Axl[2], Bxh, aNi);
            aR  = MFMA(Ah[0][0], Bl0, aR);
            aZ  = MFMA(Ah[1][0], Bl0, aZ);
            aNh = MFMA(Ah[2][0], Bl0, aNh);
            aNi = MFMA(Axh[2], Bxl, aNi);
            aR  = MFMA(Ah[0][1], Bh1, aR);
            aZ  = MFMA(Ah[1][1], Bh1, aZ);
            aNh = MFMA(Ah[2][1], Bh1, aNh);
            aR  = MFMA(Al[0][1], Bh1, aR);
            aZ  = MFMA(Al[1][1], Bh1, aZ);
            aNh = MFMA(Al[2][1], Bh1, aNh);
            aR  = MFMA(Ah[0][1], Bl1, aR);
            aZ  = MFMA(Ah[1][1], Bl1, aZ);
            aNh = MFMA(Ah[2][1], Bl1, aNh);
            aR  = MFMA(Axh[0], Bxh, aR);
            aZ  = MFMA(Axh[1], Bxh, aZ);
            aR  = MFMA(Axl[0], Bxh, aR);
            aZ  = MFMA(Axl[1], Bxh, aZ);
            aR  = MFMA(Axh[0], Bxl, aR);
            aZ  = MFMA(Axh[1], Bxl, aZ);

            // dec for t+1 (under MFMA shadow)
            if (tb + 8 < TLEN || sub < 7) {
                float dnext = (sub == 0) ? dtc0.y : (sub == 1) ? dtc0.z : (sub == 2) ? dtc0.w
                            : (sub == 3) ? dtc1.x : (sub == 4) ? dtc1.y : (sub == 5) ? dtc1.z
                            : (sub == 6) ? dtc1.w : dtn0.x;
#pragma unroll
                for (int r = 0; r < 4; ++r)
                    dcur[r] = __builtin_amdgcn_exp2f(-LOG2E * fmaxf(fmaf(dnext, wdt4[r], bdt4[r]), 0.f));
            }

            // ---- gates + h update + pred ----
            float p = 0.f;
#pragma unroll
            for (int r = 0; r < 4; ++r) {
                float rr = sigmoid2_f(aR[r]);
                float zz = sigmoid2_f(aZ[r]);
                float nn = tanh2_f(aNi[r] + rr * (aNh[r] + biasNh[r]));
                float hv = fmaf(zz, htl[r] - nn, nn);
                hreg[r] = hv;
                p = fmaf(wout4[r], hv, p);
            }
            p += __shfl_xor(p, 16, 64);
            p += __shfl_xor(p, 32, 64);
            pbuf[sub] = p;

            if (sub == 7) {
                if (l < 16) {
                    f32x4 v0 = {pbuf[0], pbuf[1], pbuf[2], pbuf[3]};
                    f32x4 v1 = {pbuf[4], pbuf[5], pbuf[6], pbuf[7]};
                    *(f32x4*)&PPc[w * 128 + n16 * 8] = v0;
                    *(f32x4*)&PPc[w * 128 + n16 * 8 + 4] = v1;
                }
                dtc0 = dtn0;
                dtc1 = dtn1;
            }
        }
    }

    // final chunk combine
    __syncthreads();
    if (tid < 128) {
        int b = tid >> 3, t8 = tid & 7;
        int base = b * 8 + t8;
        float s = PPc[base] + PPc[128 + base] + PPc[256 + base] + PPc[384 + base];
        out[(size_t)(b0g + b) * TLEN + (TLEN - 8) + t8] = s + bout;
    }
}

extern "C" void kernel_launch(void* const* d_in, const int* in_sizes, int n_in,
                              void* d_out, int out_size, void* d_ws, size_t ws_size,
                              hipStream_t stream) {
    const float* X    = (const float*)d_in[0];
    const float* dt   = (const float*)d_in[1];
    const float* w_ih = (const float*)d_in[2];
    const float* w_hh = (const float*)d_in[3];
    const float* b_ih = (const float*)d_in[4];
    const float* b_hh = (const float*)d_in[5];
    const float* w_dt = (const float*)d_in[6];
    const float* b_dt = (const float*)d_in[7];
    const float* w_out = (const float*)d_in[8];
    const float* b_out = (const float*)d_in[9];
    float* out = (float*)d_out;

    grut1_kernel<<<dim3(4096 / BT), dim3(256), 0, stream>>>(
        X, dt, w_ih, w_hh, b_ih, b_hh, w_dt, b_dt, w_out, b_out, out);
}